// Round 16
// baseline (49.946 us; speedup 1.0000x reference)
//
#include <hip/hip_runtime.h>
#include <hip/hip_fp16.h>

#define N 224        // image size
#define M 32         // CUT (number of sine modes)
#define NPIX (N * N) // 50176
#define NPLANE 384   // 128 * 3
#define PLT 128      // planes per remap group
#define NPGRP 3      // 384 / 128
#define NPT 6        // plane tiles (384/64)
#define WPB 4        // pixel windows per transpose block (pipelined)
#define NXG (784 / WPB)       // 196 window groups
#define TBLK (NXG * NPT)      // 1176 transpose blocks
#define RPX 64       // remap pixel tile
#define NCHUNK (NPIX / RPX)   // 784
#define NXCD 8
#define CPX (NCHUNK / NXCD)   // 98
#define PI_F 3.14159265358979323846f

typedef float vfloat4 __attribute__((ext_vector_type(4)));
typedef float vfloat2 __attribute__((ext_vector_type(2)));

// async 16-B global->LDS DMA (no VGPR round-trip). LDS dest is wave-uniform
// base + lane*16 (linear); global source is per-lane (pre-swizzled).
#define GLOAD16(gptr, lptr)                                                   \
    __builtin_amdgcn_global_load_lds(                                         \
        (const __attribute__((address_space(1))) void*)(gptr),                \
        (__attribute__((address_space(3))) void*)(lptr), 16, 0, 0)

// --- Fused stage 1+2. Blocks [0,224): field rows (r11 position). Blocks
// [224, 224+1176): transpose, T3/T4-pipelined: 4 windows/block, 2x16 KB LDS
// double-buffer, counted s_waitcnt vmcnt(4) (never 0 -> next window's DMAs
// stay in flight across raw s_barriers), DMA issue for window k+2 after the
// read of buffer (k&1). Swizzle unchanged from r15 (both-sides XOR, rule #21):
// source chunk cp^f(row), f=row>>2 (wave-uniform); read applies same XOR ->
// read phase 2-way bank aliasing (free).
__global__ __launch_bounds__(256) void fused_field_transpose(
    const float* __restrict__ x, const float* __restrict__ Fx,
    const float* __restrict__ Fy, int4* __restrict__ tab,
    __half* __restrict__ xt)
{
    __shared__ float pool[8192];       // 32 KB: 2 x 4096-word buffers
    const int tid = threadIdx.x;

    if (blockIdx.x < N) {
        // ---------------- field body (one block per row y) ----------------
        float* cx = pool;              // [M*M]
        float* cy = pool + M * M;      // [M*M]
        float* sy = pool + 2 * M * M;  // [M]

        const int y = blockIdx.x;

        for (int idx = tid; idx < M * M; idx += 256) {
            const int i = idx / M, j = idx % M;
            const float fi = (float)(i + 1), fj = (float)(j + 1);
            const float r = sqrtf(fi * fi + fj * fj);
            const float e = (r < (float)M + 0.5f) ? (1.0f / r) : 0.0f;
            cx[idx] = Fx[idx] * e;
            cy[idx] = Fy[idx] * e;
        }
        if (tid < M) {
            const float ys = (float)y / (float)(N - 1);
            sy[tid] = sinf(PI_F * ys * (float)(tid + 1));
        }
        __syncthreads();

        if (tid >= N) return;
        const int xi = tid;

        float sx[M];
        const float xsv = (float)xi / (float)(N - 1);
#pragma unroll
        for (int i = 0; i < M; ++i)
            sx[i] = sinf(PI_F * xsv * (float)(i + 1));

        float u = 0.0f, v = 0.0f;
#pragma unroll 1
        for (int j = 0; j < M; ++j) {
            float tx = 0.0f, ty = 0.0f;
#pragma unroll
            for (int i = 0; i < M; ++i) {
                tx = fmaf(cx[i * M + j], sx[i], tx);
                ty = fmaf(cy[i * M + j], sx[i], ty);
            }
            const float syj = sy[j];
            u = fmaf(syj, tx, u);
            v = fmaf(syj, ty, v);
        }

        const float dxv = 22.4f * u;   // sqrt(T)*n = 0.1*224
        const float dyv = 22.4f * v;
        const float xn = fminf(fmaxf((float)xi + dxv, 0.0f), (float)(N - 1));
        const float yn = fminf(fmaxf((float)y + dyv, 0.0f), (float)(N - 1));
        const int bx = min((int)floorf(xn), N - 2);
        const int by = min((int)floorf(yn), N - 2);
        const float fx = xn - (float)bx;
        const float fy = yn - (float)by;

        tab[y * N + xi] = make_int4(by * N + bx,
                                    __float_as_int(fx), __float_as_int(fy), 0);
        return;
    }

    // ---------------- pipelined transpose body ----------------
    float* const b0 = pool;
    float* const b1 = pool + 4096;

    const int tb    = blockIdx.x - N;     // 0..1175
    const int ptile = tb % NPT;           // plane tile 0..5
    const int xg    = tb / NPT;           // window group 0..195
    const int pl0   = ptile * 64;

    const int w  = tid >> 6;              // wave 0..3
    const int l  = tid & 63;
    const int r  = l >> 4;                // row-within-inst 0..3
    const int cp = l & 15;                // chunk position 0..15
    const int c  = tid & 15;              // read-phase plane quad
    const int q  = (tid >> 4) & 3;        // read-phase sub-pixel

    // issue one window's 4 DMA insts (1 KB each) into buffer bufp
#define ISSUE(win, bufp)                                                      \
    do {                                                                      \
        const int pix0_ = (xg * WPB + (win)) * 64;                            \
        _Pragma("unroll")                                                     \
        for (int i_ = 0; i_ < 4; ++i_) {                                      \
            const int row0_ = w * 16 + i_ * 4;                                \
            const int f_    = 4 * w + i_;                                     \
            GLOAD16(x + (size_t)(pl0 + row0_ + r) * NPIX + pix0_              \
                      + 4 * (cp ^ f_),                                        \
                    (bufp) + row0_ * 64);                                     \
        }                                                                     \
    } while (0)

    ISSUE(0, b0);
    ISSUE(1, b1);

#pragma unroll
    for (int k = 0; k < WPB; ++k) {
        // wait current window's DMAs only: outstanding = {DMA(k)=4 oldest,
        // stores(k-1)=4, DMA(k+1)=4} -> vmcnt(4) retires through DMA(k).
        asm volatile("s_waitcnt vmcnt(4)" ::: "memory");
        __builtin_amdgcn_sched_barrier(0);
        __builtin_amdgcn_s_barrier();
        __builtin_amdgcn_sched_barrier(0);

        const float* bufp = (k & 1) ? b1 : b0;
        const int pix0 = (xg * WPB + k) * 64;
        __half* xo = xt + (size_t)pix0 * NPLANE + pl0;
#pragma unroll
        for (int s = 0; s < 4; ++s) {
            const int P  = w * 16 + s * 4 + q;
            const int gc = (P >> 2) ^ c;      // swizzled chunk position
            const float f0 = bufp[(4 * c + 0) * 64 + gc * 4 + q];
            const float f1 = bufp[(4 * c + 1) * 64 + gc * 4 + q];
            const float f2 = bufp[(4 * c + 2) * 64 + gc * 4 + q];
            const float f3 = bufp[(4 * c + 3) * 64 + gc * 4 + q];
            union { uint2 u; __half2 hh[2]; } pk;
            pk.hh[0] = __floats2half2_rn(f0, f1);
            pk.hh[1] = __floats2half2_rn(f2, f3);
            *(uint2*)&xo[(size_t)P * NPLANE + 4 * c] = pk.u;
        }

        __builtin_amdgcn_sched_barrier(0);
        __builtin_amdgcn_s_barrier();
        __builtin_amdgcn_sched_barrier(0);

        if (k == 0) ISSUE(2, b0);
        if (k == 1) ISSUE(3, b1);
    }
#undef ISSUE
}

// --- Stage 3: remap, planes-in-lanes (round-11 version, verbatim) ----------
__global__ __launch_bounds__(256) void remap_kernel(
    const __half* __restrict__ xt, const int4* __restrict__ tab,
    float* __restrict__ out)
{
    __shared__ float tile[RPX][130];  // writes 2-way (free), reads 4-way
    __shared__ int4 ltab[RPX];

    const int tid = threadIdx.x;
    const int w = tid >> 6, l = tid & 63;

    const int bid   = blockIdx.x;
    const int xcd   = bid & 7;
    const int local = bid >> 3;          // 0..293
    const int pg    = local / CPX;       // 0..2
    const int chunk = xcd * CPX + (local % CPX);
    const int pix0  = chunk * RPX;

    if (tid < RPX) ltab[tid] = tab[pix0 + tid];
    __syncthreads();

    const __half2* base = (const __half2*)xt;
    const int pgoff = pg * (PLT / 2);    // half2 offset within a pixel row

#pragma unroll 8
    for (int i = 0; i < 16; ++i) {
        const int pl = w * 16 + i;       // pixel-local index
        const int4 tb = ltab[pl];
        const float fx = __int_as_float(tb.y);
        const float fy = __int_as_float(tb.z);
        const float omx = 1.0f - fx, omy = 1.0f - fy;
        const float w00 = omy * omx, w01 = omy * fx;
        const float w10 = fy * omx,  w11 = fy * fx;

        const size_t b0 = (size_t)tb.x * (NPLANE / 2) + pgoff;
        const float2 c00 = __half22float2(base[b0 + l]);                          // (by,  bx)
        const float2 c01 = __half22float2(base[b0 + NPLANE / 2 + l]);             // (by,  bx+1)
        const float2 c10 = __half22float2(base[b0 + (size_t)N * (NPLANE/2) + l]); // (by+1,bx)
        const float2 c11 = __half22float2(base[b0 + (size_t)(N + 1) * (NPLANE/2) + l]); // (by+1,bx+1)

        float2 o;
        o.x = w00 * c00.x + w01 * c01.x + w10 * c10.x + w11 * c11.x;
        o.y = w00 * c00.y + w01 * c01.y + w10 * c10.y + w11 * c11.y;
        *(float2*)&tile[pl][2 * l] = o;  // planes (2l,2l+1) of pixel pl
    }
    __syncthreads();

    const int l2 = tid & 31, jg = tid >> 5;   // pixel-pair, plane-group
    float* ob = out + (size_t)pg * PLT * NPIX + pix0;
#pragma unroll
    for (int s = 0; s < 16; ++s) {
        const int j = jg * 16 + s;            // plane 0..127
        vfloat2 o2;
        o2.x = tile[2 * l2][j];
        o2.y = tile[2 * l2 + 1][j];
        __builtin_nontemporal_store(o2, (vfloat2*)&ob[(size_t)j * NPIX + 2 * l2]);
    }
}

extern "C" void kernel_launch(void* const* d_in, const int* in_sizes, int n_in,
                              void* d_out, int out_size, void* d_ws, size_t ws_size,
                              hipStream_t stream) {
    const float* x  = (const float*)d_in[0];   // [128,3,224,224]
    const float* Fx = (const float*)d_in[1];   // [32,32]
    const float* Fy = (const float*)d_in[2];   // [32,32]
    float* out = (float*)d_out;

    int4* tab = (int4*)d_ws;                               // 802,816 B
    const size_t tab_bytes = (size_t)NPIX * sizeof(int4);
    __half* xt = (__half*)((char*)d_ws + tab_bytes);       // [50176][384] fp16, 38.5 MB

    fused_field_transpose<<<N + TBLK, 256, 0, stream>>>(x, Fx, Fy, tab, xt);
    remap_kernel<<<NCHUNK * NPGRP, 256, 0, stream>>>(xt, tab, out);
}